// Round 4
// baseline (152.534 us; speedup 1.0000x reference)
//
#include <hip/hip_runtime.h>
#include <stdint.h>

// SparseConv3d bf16-MFMA implicit GEMM. B=2, Cin=32, Cout=64, D=64, K=3.
// Round 4: wave owns BOTH co-halves x 2 x-tiles (8 MFMA : 4 ds_read : 4 A-load per k27),
//          block = y-quad (4 waves, 1 y each), LDS = 18 halo rows = 76KB dynamic, 2 blk/CU.
// xt layout: [b][z][y] rows of 4096B; elem (xv,ci) at u16 pos
//   xv*32 + ((ci>>3)^((xv>>1)&3))*8 + (ci&7)   (chunk-XOR swizzle baked into global layout)

#define DD 64
#define CIN 32
#define COUT 64

typedef __bf16 bf16x8 __attribute__((ext_vector_type(8)));
typedef float f32x16 __attribute__((ext_vector_type(16)));

#define XT_BYTES (2u * 64u * 64u * 64u * 32u * 2u)   // 33,554,432
#define WPK_U16  (27 * 2 * 2 * 64 * 8)               // 55,296 elems
#define WS_NEEDED (XT_BYTES + (size_t)WPK_U16 * 2)
#define CONV_LDS  (18 * 4224)                        // 76,032 B

__device__ __forceinline__ uint16_t f2bf(float f) {
    uint32_t u = __builtin_bit_cast(uint32_t, f);
    u += 0x7fffu + ((u >> 16) & 1u);   // RNE
    return (uint16_t)(u >> 16);
}

// ---------------- pre-kernel 1: weight pack ----------------
// wpk flat: (((k27*2 + cb)*2 + ct)*64 + lane)*8 + j
//   lane holds A[co = ct*32 + (lane&31)][ci = cb*16 + (lane>>5)*8 + j]
__global__ void pack_weights(const float* __restrict__ w, uint16_t* __restrict__ wpk) {
    int flat = blockIdx.x * 256 + threadIdx.x;
    if (flat >= WPK_U16) return;
    int j   = flat & 7;
    int l   = (flat >> 3) & 63;
    int ct  = (flat >> 9) & 1;
    int cb  = (flat >> 10) & 1;
    int k27 = flat >> 11;
    int co = ct * 32 + (l & 31);
    int ci = cb * 16 + ((l >> 5) * 8) + j;
    wpk[flat] = f2bf(w[(co * CIN + ci) * 27 + k27]);
}

// ---------------- pre-kernel 2: x transpose to channel-last bf16 ----------------
__global__ __launch_bounds__(256)
void transpose_x(const float* __restrict__ x, uint16_t* __restrict__ xt) {
    __shared__ uint16_t tile[2048];
    const int y = blockIdx.x, z = blockIdx.y, b = blockIdx.z;
    const int t = threadIdx.x;
    const int ci = t >> 3;
    const int xs = (t & 7) * 8;
    const float* src = x + ((((size_t)b * CIN + ci) * DD + z) * DD + y) * DD + xs;
    float4 v0 = *(const float4*)src;
    float4 v1 = *(const float4*)(src + 4);
    float vals[8] = {v0.x, v0.y, v0.z, v0.w, v1.x, v1.y, v1.z, v1.w};
#pragma unroll
    for (int e = 0; e < 8; ++e) {
        int xv = xs + e;
        int pos = xv * 32 + (((ci >> 3) ^ ((xv >> 1) & 3)) << 3) + (ci & 7);
        tile[pos] = f2bf(vals[e]);
    }
    __syncthreads();
    uint16_t* dst = xt + (((size_t)b * DD + z) * DD + y) * 2048;
    ((uint4*)dst)[t] = ((const uint4*)tile)[t];
}

// ---------------- main kernel: conv via MFMA ----------------
// block = (y-quad, z, b), 256 thr = 4 waves; wave w owns y = 4*yq + w, all 64 co, all 64 x.
__global__ __launch_bounds__(256, 2)
void conv_mfma(const uint16_t* __restrict__ xt, const uint16_t* __restrict__ wpk,
               const int* __restrict__ mask, const float* __restrict__ bias,
               float* __restrict__ out) {
    extern __shared__ __align__(16) unsigned char lds[];   // 18 rows x 4224 B
    const int yq = blockIdx.x, z = blockIdx.y, b = blockIdx.z;
    const int y0 = yq * 4;
    const int tid = threadIdx.x;
    const int lane = tid & 63;
    const int w = __builtin_amdgcn_readfirstlane(tid >> 6);

    // zero x-halo slots: 18 rows x 2 sides x 4 chunks
    for (int i = tid; i < 144; i += 256) {
        int row = i >> 3, side = (i >> 2) & 1, k = i & 3;
        *(uint4*)&lds[row * 4224 + side * 4160 + k * 16] = make_uint4(0, 0, 0, 0);
    }
    // stage 18 rows (zz in z-1..z+1, yy in y0-1..y0+4), 4KB each, reg-staged linear copy
    for (int i = w; i < 72; i += 4) {
        int row = i >> 2, kc = i & 3;
        int zz = z - 1 + (row / 6);
        int yy = y0 - 1 + (row % 6);
        uint4 v = make_uint4(0, 0, 0, 0);
        if (zz >= 0 && zz < DD && yy >= 0 && yy < DD)
            v = *(const uint4*)(xt + (((size_t)b * DD + zz) * DD + yy) * 2048 + kc * 512 + lane * 8);
        *(uint4*)&lds[row * 4224u + 64u + kc * 1024u + lane * 16u] = v;
    }
    __syncthreads();

    const int u = lane & 31;
    const int h = lane >> 5;
    const int y = y0 + w;

    f32x16 acc00, acc01, acc10, acc11;   // [ct][x-tile]
#pragma unroll
    for (int i = 0; i < 16; ++i) { acc00[i] = 0.f; acc01[i] = 0.f; acc10[i] = 0.f; acc11[i] = 0.f; }

    for (int kz = 0; kz < 3; ++kz) {
#pragma unroll
        for (int ky = 0; ky < 3; ++ky) {
            const unsigned rowbase = (unsigned)((kz * 6 + w + ky) * 4224);
#pragma unroll
            for (int kx = 0; kx < 3; ++kx) {
                const int k27 = (kz * 3 + ky) * 3 + kx;
                const int xl0 = u + kx;         // LDS x-slot, tile 0 (x = u+kx-1)
                const int xl1 = 32 + u + kx;    // tile 1
                const unsigned s0 = (((unsigned)(xl0 - 1)) >> 1) & 3u;
                const unsigned s1 = (((unsigned)(xl1 - 1)) >> 1) & 3u;
#pragma unroll
                for (int cb = 0; cb < 2; ++cb) {
                    const unsigned chunk = (unsigned)(cb * 2 + h);
                    bf16x8 a0 = *(const bf16x8*)(wpk + (size_t)((k27 * 2 + cb) * 2 + 0) * 512 + lane * 8);
                    bf16x8 a1 = *(const bf16x8*)(wpk + (size_t)((k27 * 2 + cb) * 2 + 1) * 512 + lane * 8);
                    bf16x8 b0 = *(const bf16x8*)&lds[rowbase + xl0 * 64u + ((chunk ^ s0) << 4)];
                    bf16x8 b1 = *(const bf16x8*)&lds[rowbase + xl1 * 64u + ((chunk ^ s1) << 4)];
                    acc00 = __builtin_amdgcn_mfma_f32_32x32x16_bf16(a0, b0, acc00, 0, 0, 0);
                    acc01 = __builtin_amdgcn_mfma_f32_32x32x16_bf16(a0, b1, acc01, 0, 0, 0);
                    acc10 = __builtin_amdgcn_mfma_f32_32x32x16_bf16(a1, b0, acc10, 0, 0, 0);
                    acc11 = __builtin_amdgcn_mfma_f32_32x32x16_bf16(a1, b1, acc11, 0, 0, 0);
                }
            }
        }
    }

    // epilogue: +bias, x mask, store. C layout: col = lane&31, row = (r&3)+8*(r>>2)+4*h
    const size_t mbase = (((size_t)b * DD + z) * DD + y) * DD;
    const float m0 = mask[mbase + u] ? 1.0f : 0.0f;
    const float m1 = mask[mbase + 32 + u] ? 1.0f : 0.0f;
#pragma unroll
    for (int ct = 0; ct < 2; ++ct) {
        const f32x16 A0 = ct ? acc10 : acc00;
        const f32x16 A1 = ct ? acc11 : acc01;
#pragma unroll
        for (int r = 0; r < 16; ++r) {
            int co = ct * 32 + (r & 3) + 8 * (r >> 2) + 4 * h;
            float bs = bias[co];
            size_t o = ((size_t)b * COUT + co) * (DD * DD * DD) + (size_t)z * (DD * DD) + (size_t)y * DD;
            out[o + u]      = (A0[r] + bs) * m0;
            out[o + 32 + u] = (A1[r] + bs) * m1;
        }
    }
}

// ---------------- fp32 fallback (ws too small) ----------------
#define CI_BLK 16
__global__ __launch_bounds__(256, 2)
void sparse_conv3d_f32(const float* __restrict__ x,
                       const int* __restrict__ mask,
                       const float* __restrict__ weight,
                       const float* __restrict__ bias,
                       float* __restrict__ out) {
    __shared__ float lds[9 * CI_BLK * 66];
    const int y = blockIdx.x, z = blockIdx.y, b = blockIdx.z;
    const int lane = threadIdx.x & 63;
    const int wave = __builtin_amdgcn_readfirstlane(threadIdx.x >> 6);
    float acc[16];
#pragma unroll
    for (int j = 0; j < 16; ++j) acc[j] = 0.0f;
    const int co0 = wave * 16;
    const float* wbase = weight + (size_t)co0 * (CIN * 27);
    for (int cb = 0; cb < 2; ++cb) {
        if (cb) __syncthreads();
        for (int i = wave; i < 9 * CI_BLK; i += 4) {
            const int r = i >> 4, ci_l = i & 15;
            const int zz = z + (r / 3) - 1, yy = y + (r % 3) - 1;
            const int ci = cb * CI_BLK + ci_l;
            float v = 0.0f;
            if (zz >= 0 && zz < DD && yy >= 0 && yy < DD)
                v = x[((((size_t)b * CIN + ci) * DD + zz) * DD + yy) * DD + lane];
            float* row = &lds[(size_t)i * 66];
            row[1 + lane] = v;
            if (lane == 0) { row[0] = 0.0f; row[65] = 0.0f; }
        }
        __syncthreads();
        for (int ci_l = 0; ci_l < CI_BLK; ++ci_l) {
            const int ci = cb * CI_BLK + ci_l;
#pragma unroll
            for (int kz = 0; kz < 3; ++kz) {
#pragma unroll
                for (int ky = 0; ky < 3; ++ky) {
                    const int r = kz * 3 + ky;
                    const float* xrow = &lds[(size_t)(r * CI_BLK + ci_l) * 66 + lane];
                    const float xv0 = xrow[0], xv1 = xrow[1], xv2 = xrow[2];
                    const float* wp = wbase + ci * 27 + kz * 9 + ky * 3;
#pragma unroll
                    for (int j = 0; j < 16; ++j) {
                        acc[j] += wp[(size_t)j * (CIN * 27) + 0] * xv0
                                + wp[(size_t)j * (CIN * 27) + 1] * xv1
                                + wp[(size_t)j * (CIN * 27) + 2] * xv2;
                    }
                }
            }
        }
    }
    const float m = mask[(((size_t)b * DD + z) * DD + y) * DD + lane] ? 1.0f : 0.0f;
#pragma unroll
    for (int j = 0; j < 16; ++j) {
        const int co = co0 + j;
        out[((((size_t)b * COUT + co) * DD + z) * DD + y) * DD + lane] = (acc[j] + bias[co]) * m;
    }
}

extern "C" void kernel_launch(void* const* d_in, const int* in_sizes, int n_in,
                              void* d_out, int out_size, void* d_ws, size_t ws_size,
                              hipStream_t stream) {
    const float* x    = (const float*)d_in[0];
    const int*   mask = (const int*)d_in[1];
    const float* w    = (const float*)d_in[2];
    const float* bias = (const float*)d_in[3];
    float*       out  = (float*)d_out;

    if (ws_size < WS_NEEDED) {
        sparse_conv3d_f32<<<dim3(DD, DD, 2), 256, 0, stream>>>(x, mask, w, bias, out);
        return;
    }

    uint16_t* xt  = (uint16_t*)d_ws;
    uint16_t* wpk = (uint16_t*)((char*)d_ws + XT_BYTES);

    pack_weights<<<(WPK_U16 + 255) / 256, 256, 0, stream>>>(w, wpk);
    transpose_x<<<dim3(DD, DD, 2), 256, 0, stream>>>(x, xt);
    conv_mfma<<<dim3(DD / 4, DD, 2), 256, CONV_LDS, stream>>>(xt, wpk, mask, bias, out);
}

// Round 5
// 120.688 us; speedup vs baseline: 1.2639x; 1.2639x over previous
//
#include <hip/hip_runtime.h>
#include <stdint.h>

// SparseConv3d bf16-MFMA implicit GEMM. B=2, Cin=32, Cout=64, D=64, K=3.
// Round 5: weights held in VGPRs (loaded once/block) -- kills the per-k-step
//   A-load latency chain that bound rounds 3/4 (~700 cyc/load serialized).
//   Block = (y-quad, z, b*2+ct): 4 waves = (wy y-pair) x (cb ci-half).
//   Wave: 27 weight frags in regs; loop over 12 LDS rows; 6 ds_read_b128 ->
//   3-6 MFMAs per row (B-frag reused across the y-pair). 72 ds : 108 MFMA.
//   cb-partials reduced via LDS (stride-20-word, conflict-free b128).
// xt layout: [b][z][y] rows of 4096B; elem (xv,ci) at u16 pos
//   xv*32 + ((ci>>3)^((xv>>1)&3))*8 + (ci&7)   (swizzle baked into global layout)

#define DD 64
#define CIN 32
#define COUT 64

typedef __bf16 bf16x8 __attribute__((ext_vector_type(8)));
typedef float f32x16 __attribute__((ext_vector_type(16)));

#define XT_BYTES (2u * 64u * 64u * 64u * 32u * 2u)   // 33,554,432
#define WPK_U16  (27 * 2 * 2 * 64 * 8)               // 55,296 elems
#define WS_NEEDED (XT_BYTES + (size_t)WPK_U16 * 2)
#define CONV_LDS  (18 * 4224)                        // 76,032 B

__device__ __forceinline__ uint16_t f2bf(float f) {
    uint32_t u = __builtin_bit_cast(uint32_t, f);
    u += 0x7fffu + ((u >> 16) & 1u);   // RNE
    return (uint16_t)(u >> 16);
}

// ---------------- pre-kernel 1: weight pack ----------------
// wpk flat: (((k27*2 + cb)*2 + ct)*64 + lane)*8 + j
//   lane holds A[co = ct*32 + (lane&31)][ci = cb*16 + (lane>>5)*8 + j]
__global__ void pack_weights(const float* __restrict__ w, uint16_t* __restrict__ wpk) {
    int flat = blockIdx.x * 256 + threadIdx.x;
    if (flat >= WPK_U16) return;
    int j   = flat & 7;
    int l   = (flat >> 3) & 63;
    int ct  = (flat >> 9) & 1;
    int cb  = (flat >> 10) & 1;
    int k27 = flat >> 11;
    int co = ct * 32 + (l & 31);
    int ci = cb * 16 + ((l >> 5) * 8) + j;
    wpk[flat] = f2bf(w[(co * CIN + ci) * 27 + k27]);
}

// ---------------- pre-kernel 2: x transpose to channel-last bf16 ----------------
__global__ __launch_bounds__(256)
void transpose_x(const float* __restrict__ x, uint16_t* __restrict__ xt) {
    __shared__ uint16_t tile[2048];
    const int y = blockIdx.x, z = blockIdx.y, b = blockIdx.z;
    const int t = threadIdx.x;
    const int ci = t >> 3;
    const int xs = (t & 7) * 8;
    const float* src = x + ((((size_t)b * CIN + ci) * DD + z) * DD + y) * DD + xs;
    float4 v0 = *(const float4*)src;
    float4 v1 = *(const float4*)(src + 4);
    float vals[8] = {v0.x, v0.y, v0.z, v0.w, v1.x, v1.y, v1.z, v1.w};
#pragma unroll
    for (int e = 0; e < 8; ++e) {
        int xv = xs + e;
        int pos = xv * 32 + (((ci >> 3) ^ ((xv >> 1) & 3)) << 3) + (ci & 7);
        tile[pos] = f2bf(vals[e]);
    }
    __syncthreads();
    uint16_t* dst = xt + (((size_t)b * DD + z) * DD + y) * 2048;
    ((uint4*)dst)[t] = ((const uint4*)tile)[t];
}

// ---------------- main kernel ----------------
// grid = (yq 16, z 64, b*2+ct 4); 256 thr = 4 waves: w = wy*2 + cb.
__global__ __launch_bounds__(256, 2)
void conv_mfma(const uint16_t* __restrict__ xt, const uint16_t* __restrict__ wpk,
               const int* __restrict__ mask, const float* __restrict__ bias,
               float* __restrict__ out) {
    extern __shared__ __align__(16) unsigned char lds[];   // 18 rows x 4224 B
    const int yq = blockIdx.x, z = blockIdx.y;
    const int b  = blockIdx.z >> 1, ct = blockIdx.z & 1;
    const int y0 = yq * 4;
    const int tid = threadIdx.x;
    const int lane = tid & 63;
    const int w = __builtin_amdgcn_readfirstlane(tid >> 6);
    const int wy = w >> 1;   // which y-pair of the quad
    const int cb = w & 1;    // which ci-half

    // ---- zero x-halo slots: 18 rows x 2 sides x 4 chunks ----
    for (int i = tid; i < 144; i += 256) {
        int row = i >> 3, side = (i >> 2) & 1, k = i & 3;
        *(uint4*)&lds[row * 4224 + side * 4160 + k * 16] = make_uint4(0, 0, 0, 0);
    }
    // ---- stage 18 rows (zz in z-1..z+1, yy in y0-1..y0+4), reg-staged linear ----
    for (int i = w; i < 72; i += 4) {
        int row = i >> 2, kc = i & 3;
        int zz = z - 1 + (row / 6);
        int yy = y0 - 1 + (row % 6);
        uint4 v = make_uint4(0, 0, 0, 0);
        if (zz >= 0 && zz < DD && yy >= 0 && yy < DD)
            v = *(const uint4*)(xt + (((size_t)b * DD + zz) * DD + yy) * 2048 + kc * 512 + lane * 8);
        *(uint4*)&lds[row * 4224u + 64u + kc * 1024u + lane * 16u] = v;
    }
    __syncthreads();

    const int u = lane & 31;
    const int h = lane >> 5;
    const int ya = y0 + 2 * wy;
    const unsigned cc = (unsigned)(cb * 2 + h);

    f32x16 accA0, accA1, accB0, accB1;   // (y=ya,x-tile0/1), (y=ya+1,x-tile0/1)
#pragma unroll
    for (int i = 0; i < 16; ++i) { accA0[i] = 0.f; accA1[i] = 0.f; accB0[i] = 0.f; accB1[i] = 0.f; }

#pragma unroll
    for (int zr = 0; zr < 3; ++zr) {
        // weights for this kz: 9 frags -> VGPRs (reloaded per zr to bound reg pressure)
        bf16x8 wf[9];
#pragma unroll
        for (int q = 0; q < 9; ++q) {
            const int k27 = zr * 9 + q;
            wf[q] = *(const bf16x8*)(wpk + (size_t)((k27 * 2 + cb) * 2 + ct) * 512 + lane * 8);
        }
#pragma unroll
        for (int t = 0; t < 4; ++t) {
            const unsigned rb = (unsigned)((zr * 6 + 2 * wy + t) * 4224);
            bf16x8 bf0[3], bf1[3];
#pragma unroll
            for (int kx = 0; kx < 3; ++kx) {
                const unsigned sl0 = (unsigned)(u + kx);
                const unsigned sl1 = sl0 + 32u;
                const unsigned s0 = ((sl0 - 1u) >> 1) & 3u;   // slot 0 is zero-halo: any chunk ok
                const unsigned s1 = ((sl1 - 1u) >> 1) & 3u;
                bf0[kx] = *(const bf16x8*)&lds[rb + sl0 * 64u + ((cc ^ s0) << 4)];
                bf1[kx] = *(const bf16x8*)&lds[rb + sl1 * 64u + ((cc ^ s1) << 4)];
            }
            if (t <= 2) {   // output y = ya, ky = t
#pragma unroll
                for (int kx = 0; kx < 3; ++kx) {
                    accA0 = __builtin_amdgcn_mfma_f32_32x32x16_bf16(wf[t * 3 + kx], bf0[kx], accA0, 0, 0, 0);
                    accA1 = __builtin_amdgcn_mfma_f32_32x32x16_bf16(wf[t * 3 + kx], bf1[kx], accA1, 0, 0, 0);
                }
            }
            if (t >= 1) {   // output y = ya+1, ky = t-1
#pragma unroll
                for (int kx = 0; kx < 3; ++kx) {
                    accB0 = __builtin_amdgcn_mfma_f32_32x32x16_bf16(wf[(t - 1) * 3 + kx], bf0[kx], accB0, 0, 0, 0);
                    accB1 = __builtin_amdgcn_mfma_f32_32x32x16_bf16(wf[(t - 1) * 3 + kx], bf1[kx], accB1, 0, 0, 0);
                }
            }
        }
    }

    // ---- cross-wave (cb) reduction via LDS; stride 20 words = conflict-free b128 ----
    __syncthreads();   // all x-tile reads done; LDS reusable
    float* pb = (float*)lds;

#define STORE_PARTIAL(A, aidx)                                                     \
    {   const unsigned base = (unsigned)((wy * 4 + (aidx)) * 1280 + lane * 20);    \
        *(float4*)&pb[base +  0] = make_float4(A[0],  A[1],  A[2],  A[3]);         \
        *(float4*)&pb[base +  4] = make_float4(A[4],  A[5],  A[6],  A[7]);         \
        *(float4*)&pb[base +  8] = make_float4(A[8],  A[9],  A[10], A[11]);        \
        *(float4*)&pb[base + 12] = make_float4(A[12], A[13], A[14], A[15]); }

#define ADD_PARTIAL(A, aidx)                                                       \
    {   const unsigned base = (unsigned)((wy * 4 + (aidx)) * 1280 + lane * 20);    \
        float4 p0 = *(const float4*)&pb[base +  0];                                \
        float4 p1 = *(const float4*)&pb[base +  4];                                \
        float4 p2 = *(const float4*)&pb[base +  8];                                \
        float4 p3 = *(const float4*)&pb[base + 12];                                \
        A[0] += p0.x;  A[1] += p0.y;  A[2]  += p0.z;  A[3]  += p0.w;               \
        A[4] += p1.x;  A[5] += p1.y;  A[6]  += p1.z;  A[7]  += p1.w;               \
        A[8] += p2.x;  A[9] += p2.y;  A[10] += p2.z;  A[11] += p2.w;               \
        A[12] += p3.x; A[13] += p3.y; A[14] += p3.z;  A[15] += p3.w; }

    if (cb == 1) {
        STORE_PARTIAL(accA0, 0)
        STORE_PARTIAL(accA1, 1)
        STORE_PARTIAL(accB0, 2)
        STORE_PARTIAL(accB1, 3)
    }
    __syncthreads();
    if (cb == 0) {
        ADD_PARTIAL(accA0, 0)
        ADD_PARTIAL(accA1, 1)
        ADD_PARTIAL(accB0, 2)
        ADD_PARTIAL(accB1, 3)

        // ---- epilogue: +bias, x mask, store. C: col = u (x), row = (r&3)+8*(r>>2)+4*h (co) ----
        const size_t mb0 = (((size_t)b * DD + z) * DD + ya) * DD;
        const float m00 = mask[mb0 + u]           ? 1.0f : 0.0f;
        const float m01 = mask[mb0 + 32 + u]      ? 1.0f : 0.0f;
        const float m10 = mask[mb0 + DD + u]      ? 1.0f : 0.0f;
        const float m11 = mask[mb0 + DD + 32 + u] ? 1.0f : 0.0f;
#pragma unroll
        for (int r = 0; r < 16; ++r) {
            const int co = ct * 32 + (r & 3) + 8 * (r >> 2) + 4 * h;
            const float bs = bias[co];
            const size_t o = ((size_t)b * COUT + co) * (DD * DD * DD)
                           + (size_t)z * (DD * DD) + (size_t)ya * DD;
            out[o + u]           = (accA0[r] + bs) * m00;
            out[o + 32 + u]      = (accA1[r] + bs) * m01;
            out[o + DD + u]      = (accB0[r] + bs) * m10;
            out[o + DD + 32 + u] = (accB1[r] + bs) * m11;
        }
    }
#undef STORE_PARTIAL
#undef ADD_PARTIAL
}

// ---------------- fp32 fallback (ws too small) ----------------
#define CI_BLK 16
__global__ __launch_bounds__(256, 2)
void sparse_conv3d_f32(const float* __restrict__ x,
                       const int* __restrict__ mask,
                       const float* __restrict__ weight,
                       const float* __restrict__ bias,
                       float* __restrict__ out) {
    __shared__ float lds[9 * CI_BLK * 66];
    const int y = blockIdx.x, z = blockIdx.y, b = blockIdx.z;
    const int lane = threadIdx.x & 63;
    const int wave = __builtin_amdgcn_readfirstlane(threadIdx.x >> 6);
    float acc[16];
#pragma unroll
    for (int j = 0; j < 16; ++j) acc[j] = 0.0f;
    const int co0 = wave * 16;
    const float* wbase = weight + (size_t)co0 * (CIN * 27);
    for (int cbl = 0; cbl < 2; ++cbl) {
        if (cbl) __syncthreads();
        for (int i = wave; i < 9 * CI_BLK; i += 4) {
            const int r = i >> 4, ci_l = i & 15;
            const int zz = z + (r / 3) - 1, yy = y + (r % 3) - 1;
            const int ci = cbl * CI_BLK + ci_l;
            float v = 0.0f;
            if (zz >= 0 && zz < DD && yy >= 0 && yy < DD)
                v = x[((((size_t)b * CIN + ci) * DD + zz) * DD + yy) * DD + lane];
            float* row = &lds[(size_t)i * 66];
            row[1 + lane] = v;
            if (lane == 0) { row[0] = 0.0f; row[65] = 0.0f; }
        }
        __syncthreads();
        for (int ci_l = 0; ci_l < CI_BLK; ++ci_l) {
            const int ci = cbl * CI_BLK + ci_l;
#pragma unroll
            for (int kz = 0; kz < 3; ++kz) {
#pragma unroll
                for (int ky = 0; ky < 3; ++ky) {
                    const int r = kz * 3 + ky;
                    const float* xrow = &lds[(size_t)(r * CI_BLK + ci_l) * 66 + lane];
                    const float xv0 = xrow[0], xv1 = xrow[1], xv2 = xrow[2];
                    const float* wp = wbase + ci * 27 + kz * 9 + ky * 3;
#pragma unroll
                    for (int j = 0; j < 16; ++j) {
                        acc[j] += wp[(size_t)j * (CIN * 27) + 0] * xv0
                                + wp[(size_t)j * (CIN * 27) + 1] * xv1
                                + wp[(size_t)j * (CIN * 27) + 2] * xv2;
                    }
                }
            }
        }
    }
    const float m = mask[(((size_t)b * DD + z) * DD + y) * DD + lane] ? 1.0f : 0.0f;
#pragma unroll
    for (int j = 0; j < 16; ++j) {
        const int co = co0 + j;
        out[((((size_t)b * COUT + co) * DD + z) * DD + y) * DD + lane] = (acc[j] + bias[co]) * m;
    }
}

extern "C" void kernel_launch(void* const* d_in, const int* in_sizes, int n_in,
                              void* d_out, int out_size, void* d_ws, size_t ws_size,
                              hipStream_t stream) {
    const float* x    = (const float*)d_in[0];
    const int*   mask = (const int*)d_in[1];
    const float* w    = (const float*)d_in[2];
    const float* bias = (const float*)d_in[3];
    float*       out  = (float*)d_out;

    if (ws_size < WS_NEEDED) {
        sparse_conv3d_f32<<<dim3(DD, DD, 2), 256, 0, stream>>>(x, mask, w, bias, out);
        return;
    }

    uint16_t* xt  = (uint16_t*)d_ws;
    uint16_t* wpk = (uint16_t*)((char*)d_ws + XT_BYTES);

    pack_weights<<<(WPK_U16 + 255) / 256, 256, 0, stream>>>(w, wpk);
    transpose_x<<<dim3(DD, DD, 2), 256, 0, stream>>>(x, xt);
    conv_mfma<<<dim3(DD / 4, DD, 4), 256, CONV_LDS, stream>>>(xt, wpk, mask, bias, out);
}

// Round 6
// 92.925 us; speedup vs baseline: 1.6415x; 1.2988x over previous
//
#include <hip/hip_runtime.h>
#include <stdint.h>

// SparseConv3d bf16-MFMA implicit GEMM. B=2, Cin=32, Cout=64, D=64, K=3.
// Round 6: one 512-thread block = 8 waves (ct, x-tile, wy); each wave loops both
//   ci-halves -> NO cross-wave reduction, all waves store. 16 waves/CU (2 blocks
//   x 76KB LDS). Per wave: 72 ds_read_b128 : 108 MFMA; accs = 32 VGPR;
//   weights 9 frags per (zr,cb) phase from L2-resident wpk. launch_bounds(512,4).
// xt layout: [b][z][y] rows of 4096B; elem (xv,ci) at u16 pos
//   xv*32 + ((ci>>3)^((xv>>1)&3))*8 + (ci&7)   (swizzle baked into global layout)

#define DD 64
#define CIN 32
#define COUT 64

typedef __bf16 bf16x8 __attribute__((ext_vector_type(8)));
typedef float f32x16 __attribute__((ext_vector_type(16)));

#define XT_BYTES (2u * 64u * 64u * 64u * 32u * 2u)   // 33,554,432
#define WPK_U16  (27 * 2 * 2 * 64 * 8)               // 55,296 elems
#define WS_NEEDED (XT_BYTES + (size_t)WPK_U16 * 2)
#define CONV_LDS  (18 * 4224)                        // 76,032 B

__device__ __forceinline__ uint16_t f2bf(float f) {
    uint32_t u = __builtin_bit_cast(uint32_t, f);
    u += 0x7fffu + ((u >> 16) & 1u);   // RNE
    return (uint16_t)(u >> 16);
}

// ---------------- pre-kernel 1: weight pack ----------------
// wpk flat: (((k27*2 + cb)*2 + ct)*64 + lane)*8 + j
//   lane holds A[co = ct*32 + (lane&31)][ci = cb*16 + (lane>>5)*8 + j]
__global__ void pack_weights(const float* __restrict__ w, uint16_t* __restrict__ wpk) {
    int flat = blockIdx.x * 256 + threadIdx.x;
    if (flat >= WPK_U16) return;
    int j   = flat & 7;
    int l   = (flat >> 3) & 63;
    int ct  = (flat >> 9) & 1;
    int cb  = (flat >> 10) & 1;
    int k27 = flat >> 11;
    int co = ct * 32 + (l & 31);
    int ci = cb * 16 + ((l >> 5) * 8) + j;
    wpk[flat] = f2bf(w[(co * CIN + ci) * 27 + k27]);
}

// ---------------- pre-kernel 2: x transpose to channel-last bf16 ----------------
__global__ __launch_bounds__(256)
void transpose_x(const float* __restrict__ x, uint16_t* __restrict__ xt) {
    __shared__ uint16_t tile[2048];
    const int y = blockIdx.x, z = blockIdx.y, b = blockIdx.z;
    const int t = threadIdx.x;
    const int ci = t >> 3;
    const int xs = (t & 7) * 8;
    const float* src = x + ((((size_t)b * CIN + ci) * DD + z) * DD + y) * DD + xs;
    float4 v0 = *(const float4*)src;
    float4 v1 = *(const float4*)(src + 4);
    float vals[8] = {v0.x, v0.y, v0.z, v0.w, v1.x, v1.y, v1.z, v1.w};
#pragma unroll
    for (int e = 0; e < 8; ++e) {
        int xv = xs + e;
        int pos = xv * 32 + (((ci >> 3) ^ ((xv >> 1) & 3)) << 3) + (ci & 7);
        tile[pos] = f2bf(vals[e]);
    }
    __syncthreads();
    uint16_t* dst = xt + (((size_t)b * DD + z) * DD + y) * 2048;
    ((uint4*)dst)[t] = ((const uint4*)tile)[t];
}

// ---------------- main kernel ----------------
// grid = (yq 16, z 64, b 2); 512 thr = 8 waves: w = (wy<<2) | (xt<<1) | ct.
__global__ __launch_bounds__(512, 4)
void conv_mfma(const uint16_t* __restrict__ xt, const uint16_t* __restrict__ wpk,
               const int* __restrict__ mask, const float* __restrict__ bias,
               float* __restrict__ out) {
    extern __shared__ __align__(16) unsigned char lds[];   // 18 rows x 4224 B
    const int yq = blockIdx.x, z = blockIdx.y, b = blockIdx.z;
    const int y0 = yq * 4;
    const int tid = threadIdx.x;
    const int lane = tid & 63;
    const int w = __builtin_amdgcn_readfirstlane(tid >> 6);
    const int ct = w & 1;          // co half
    const int xtile = (w >> 1) & 1; // x half
    const int wy = w >> 2;          // y-pair of the quad

    // ---- zero x-halo slots: 18 rows x 2 sides x 4 chunks ----
    for (int i = tid; i < 144; i += 512) {
        int row = i >> 3, side = (i >> 2) & 1, k = i & 3;
        *(uint4*)&lds[row * 4224 + side * 4160 + k * 16] = make_uint4(0, 0, 0, 0);
    }
    // ---- stage 18 rows (zz in z-1..z+1, yy in y0-1..y0+4), reg-staged linear ----
    for (int i = w; i < 72; i += 8) {
        int row = i >> 2, kc = i & 3;
        int zz = z - 1 + (row / 6);
        int yy = y0 - 1 + (row % 6);
        uint4 v = make_uint4(0, 0, 0, 0);
        if (zz >= 0 && zz < DD && yy >= 0 && yy < DD)
            v = *(const uint4*)(xt + (((size_t)b * DD + zz) * DD + yy) * 2048 + kc * 512 + lane * 8);
        *(uint4*)&lds[row * 4224u + 64u + kc * 1024u + lane * 16u] = v;
    }
    __syncthreads();

    const int u = lane & 31;
    const int h = lane >> 5;
    const int ya = y0 + 2 * wy;
    const int xoff = xtile * 32;

    f32x16 accA, accB;   // y = ya, ya+1 (this wave's x-tile, co-half)
#pragma unroll
    for (int i = 0; i < 16; ++i) { accA[i] = 0.f; accB[i] = 0.f; }

#pragma unroll
    for (int zr = 0; zr < 3; ++zr) {
#pragma unroll
        for (int cb = 0; cb < 2; ++cb) {
            // 9 weight frags for (zr, cb, ct) -> VGPRs
            bf16x8 wf[9];
#pragma unroll
            for (int q = 0; q < 9; ++q) {
                const int k27 = zr * 9 + q;
                wf[q] = *(const bf16x8*)(wpk + (size_t)((k27 * 2 + cb) * 2 + ct) * 512 + lane * 8);
            }
            const unsigned cc = (unsigned)(cb * 2 + h);
#pragma unroll
            for (int t = 0; t < 4; ++t) {
                const unsigned rb = (unsigned)((zr * 6 + 2 * wy + t) * 4224);
                bf16x8 bf[3];
#pragma unroll
                for (int kx = 0; kx < 3; ++kx) {
                    const unsigned sl = (unsigned)(xoff + u + kx);
                    const unsigned s = ((sl - 1u) >> 1) & 3u;   // slot 0 is zero-halo: any chunk ok
                    bf[kx] = *(const bf16x8*)&lds[rb + sl * 64u + ((cc ^ s) << 4)];
                }
                if (t <= 2) {   // output y = ya, ky = t
#pragma unroll
                    for (int kx = 0; kx < 3; ++kx)
                        accA = __builtin_amdgcn_mfma_f32_32x32x16_bf16(wf[t * 3 + kx], bf[kx], accA, 0, 0, 0);
                }
                if (t >= 1) {   // output y = ya+1, ky = t-1
#pragma unroll
                    for (int kx = 0; kx < 3; ++kx)
                        accB = __builtin_amdgcn_mfma_f32_32x32x16_bf16(wf[(t - 1) * 3 + kx], bf[kx], accB, 0, 0, 0);
                }
            }
        }
    }

    // ---- epilogue: +bias, x mask, store. C: col = u (x within tile), row = (r&3)+8*(r>>2)+4*h (co) ----
    const size_t mb0 = (((size_t)b * DD + z) * DD + ya) * DD;
    const float m0 = mask[mb0 + xoff + u]      ? 1.0f : 0.0f;
    const float m1 = mask[mb0 + DD + xoff + u] ? 1.0f : 0.0f;
#pragma unroll
    for (int r = 0; r < 16; ++r) {
        const int co = ct * 32 + (r & 3) + 8 * (r >> 2) + 4 * h;
        const float bs = bias[co];
        const size_t o = ((size_t)b * COUT + co) * (DD * DD * DD)
                       + (size_t)z * (DD * DD) + (size_t)ya * DD + xoff;
        out[o + u]      = (accA[r] + bs) * m0;
        out[o + DD + u] = (accB[r] + bs) * m1;
    }
}

// ---------------- fp32 fallback (ws too small) ----------------
#define CI_BLK 16
__global__ __launch_bounds__(256, 2)
void sparse_conv3d_f32(const float* __restrict__ x,
                       const int* __restrict__ mask,
                       const float* __restrict__ weight,
                       const float* __restrict__ bias,
                       float* __restrict__ out) {
    __shared__ float lds[9 * CI_BLK * 66];
    const int y = blockIdx.x, z = blockIdx.y, b = blockIdx.z;
    const int lane = threadIdx.x & 63;
    const int wave = __builtin_amdgcn_readfirstlane(threadIdx.x >> 6);
    float acc[16];
#pragma unroll
    for (int j = 0; j < 16; ++j) acc[j] = 0.0f;
    const int co0 = wave * 16;
    const float* wbase = weight + (size_t)co0 * (CIN * 27);
    for (int cbl = 0; cbl < 2; ++cbl) {
        if (cbl) __syncthreads();
        for (int i = wave; i < 9 * CI_BLK; i += 4) {
            const int r = i >> 4, ci_l = i & 15;
            const int zz = z + (r / 3) - 1, yy = y + (r % 3) - 1;
            const int ci = cbl * CI_BLK + ci_l;
            float v = 0.0f;
            if (zz >= 0 && zz < DD && yy >= 0 && yy < DD)
                v = x[((((size_t)b * CIN + ci) * DD + zz) * DD + yy) * DD + lane];
            float* row = &lds[(size_t)i * 66];
            row[1 + lane] = v;
            if (lane == 0) { row[0] = 0.0f; row[65] = 0.0f; }
        }
        __syncthreads();
        for (int ci_l = 0; ci_l < CI_BLK; ++ci_l) {
            const int ci = cbl * CI_BLK + ci_l;
#pragma unroll
            for (int kz = 0; kz < 3; ++kz) {
#pragma unroll
                for (int ky = 0; ky < 3; ++ky) {
                    const int r = kz * 3 + ky;
                    const float* xrow = &lds[(size_t)(r * CI_BLK + ci_l) * 66 + lane];
                    const float xv0 = xrow[0], xv1 = xrow[1], xv2 = xrow[2];
                    const float* wp = wbase + ci * 27 + kz * 9 + ky * 3;
#pragma unroll
                    for (int j = 0; j < 16; ++j) {
                        acc[j] += wp[(size_t)j * (CIN * 27) + 0] * xv0
                                + wp[(size_t)j * (CIN * 27) + 1] * xv1
                                + wp[(size_t)j * (CIN * 27) + 2] * xv2;
                    }
                }
            }
        }
    }
    const float m = mask[(((size_t)b * DD + z) * DD + y) * DD + lane] ? 1.0f : 0.0f;
#pragma unroll
    for (int j = 0; j < 16; ++j) {
        const int co = co0 + j;
        out[((((size_t)b * COUT + co) * DD + z) * DD + y) * DD + lane] = (acc[j] + bias[co]) * m;
    }
}

extern "C" void kernel_launch(void* const* d_in, const int* in_sizes, int n_in,
                              void* d_out, int out_size, void* d_ws, size_t ws_size,
                              hipStream_t stream) {
    const float* x    = (const float*)d_in[0];
    const int*   mask = (const int*)d_in[1];
    const float* w    = (const float*)d_in[2];
    const float* bias = (const float*)d_in[3];
    float*       out  = (float*)d_out;

    if (ws_size < WS_NEEDED) {
        sparse_conv3d_f32<<<dim3(DD, DD, 2), 256, 0, stream>>>(x, mask, w, bias, out);
        return;
    }

    uint16_t* xt  = (uint16_t*)d_ws;
    uint16_t* wpk = (uint16_t*)((char*)d_ws + XT_BYTES);

    pack_weights<<<(WPK_U16 + 255) / 256, 256, 0, stream>>>(w, wpk);
    transpose_x<<<dim3(DD, DD, 2), 256, 0, stream>>>(x, xt);
    conv_mfma<<<dim3(DD / 4, DD, 2), 512, CONV_LDS, stream>>>(xt, wpk, mask, bias, out);
}

// Round 7
// 88.790 us; speedup vs baseline: 1.7179x; 1.0466x over previous
//
#include <hip/hip_runtime.h>
#include <stdint.h>

// SparseConv3d bf16-MFMA implicit GEMM. B=2, Cin=32, Cout=64, D=64, K=3.
// Round 7: y-quad per wave (3x B-frag reuse) + z-plane double-buffered pipeline
//   (stage plane k+1 via global_load_lds while computing plane k) + 3 blocks/CU
//   (LDS 50.7KB). Block = 4 waves (ct x xtile); each wave: 4y x 32x x 32co.
//   Per phase(zr,cb): 18 ds_read_b128 : 36 MFMA. OOB staging reads a zero page.
// xt layout: [b][z][y] rows of 4096B; elem (xv,ci) at u16 pos
//   xv*32 + ((ci>>3)^((xv>>1)&3))*8 + (ci&7)   (swizzle baked into global layout)

#define DD 64
#define CIN 32
#define COUT 64

typedef __bf16 bf16x8 __attribute__((ext_vector_type(8)));
typedef float f32x16 __attribute__((ext_vector_type(16)));

#define XT_BYTES  (2u * 64u * 64u * 64u * 32u * 2u)   // 33,554,432
#define WPK_U16   (27 * 2 * 2 * 64 * 8)               // 55,296 elems
#define WPK_BYTES ((size_t)WPK_U16 * 2)               // 110,592
#define ZP_BYTES  1024
#define WS_NEEDED (XT_BYTES + WPK_BYTES + ZP_BYTES)
#define BUF_STRIDE 25344u                             // 6 rows x 4224
#define CONV_LDS  (2 * 25344)                         // 50,688 B

__device__ __forceinline__ uint16_t f2bf(float f) {
    uint32_t u = __builtin_bit_cast(uint32_t, f);
    u += 0x7fffu + ((u >> 16) & 1u);   // RNE
    return (uint16_t)(u >> 16);
}

// async global->LDS, 16B/lane. LDS dest = wave-uniform base (HW adds lane*16).
__device__ __forceinline__ void gll16(const void* g, void* l) {
    __builtin_amdgcn_global_load_lds(
        (__attribute__((address_space(1))) void*)g,
        (__attribute__((address_space(3))) void*)l, 16, 0, 0);
}

// ---------------- pre-kernel 1: weight pack (+ zero page) ----------------
// wpk flat: (((k27*2 + cb)*2 + ct)*64 + lane)*8 + j
//   lane holds A[co = ct*32 + (lane&31)][ci = cb*16 + (lane>>5)*8 + j]
__global__ void pack_weights(const float* __restrict__ w, uint16_t* __restrict__ wpk,
                             uint4* __restrict__ zp) {
    int flat = blockIdx.x * 256 + threadIdx.x;
    if (flat < WPK_U16) {
        int j   = flat & 7;
        int l   = (flat >> 3) & 63;
        int ct  = (flat >> 9) & 1;
        int cb  = (flat >> 10) & 1;
        int k27 = flat >> 11;
        int co = ct * 32 + (l & 31);
        int ci = cb * 16 + ((l >> 5) * 8) + j;
        wpk[flat] = f2bf(w[(co * CIN + ci) * 27 + k27]);
    } else if (flat - WPK_U16 < ZP_BYTES / 16) {
        zp[flat - WPK_U16] = make_uint4(0, 0, 0, 0);
    }
}

// ---------------- pre-kernel 2: x transpose to channel-last bf16 ----------------
__global__ __launch_bounds__(256)
void transpose_x(const float* __restrict__ x, uint16_t* __restrict__ xt) {
    __shared__ uint16_t tile[2048];
    const int y = blockIdx.x, z = blockIdx.y, b = blockIdx.z;
    const int t = threadIdx.x;
    const int ci = t >> 3;
    const int xs = (t & 7) * 8;
    const float* src = x + ((((size_t)b * CIN + ci) * DD + z) * DD + y) * DD + xs;
    float4 v0 = *(const float4*)src;
    float4 v1 = *(const float4*)(src + 4);
    float vals[8] = {v0.x, v0.y, v0.z, v0.w, v1.x, v1.y, v1.z, v1.w};
#pragma unroll
    for (int e = 0; e < 8; ++e) {
        int xv = xs + e;
        int pos = xv * 32 + (((ci >> 3) ^ ((xv >> 1) & 3)) << 3) + (ci & 7);
        tile[pos] = f2bf(vals[e]);
    }
    __syncthreads();
    uint16_t* dst = xt + (((size_t)b * DD + z) * DD + y) * 2048;
    ((uint4*)dst)[t] = ((const uint4*)tile)[t];
}

// ---------------- main kernel ----------------
// grid = (yq 16, z 64, b 2); 256 thr = 4 waves: w = xtile*2 + ct. Wave: y-quad x 32x x 32co.
__global__ __launch_bounds__(256, 3)
void conv_mfma(const uint16_t* __restrict__ xt, const uint16_t* __restrict__ wpk,
               const uint16_t* __restrict__ zp,
               const int* __restrict__ mask, const float* __restrict__ bias,
               float* __restrict__ out) {
    extern __shared__ __align__(16) unsigned char lds[];   // 2 x 6 rows x 4224
    const int yq = blockIdx.x, z = blockIdx.y, b = blockIdx.z;
    const int y0 = yq * 4;
    const int tid = threadIdx.x;
    const int lane = tid & 63;
    const int w = __builtin_amdgcn_readfirstlane(tid >> 6);
    const int ct    = w & 1;          // co half
    const int xtile = (w >> 1) & 1;   // x half
    const int u = lane & 31;
    const int h = lane >> 5;
    const int xoff = xtile * 32;

    // ---- zero x-halo slots: 2 bufs x 6 rows x 2 sides x 4 chunks = 96 ----
    if (tid < 96) {
        int bb = tid >= 48, j = tid - bb * 48;
        int row = j >> 3, side = (j >> 2) & 1, k = j & 3;
        *(uint4*)&lds[bb * BUF_STRIDE + row * 4224 + side * 4160 + k * 16] = make_uint4(0, 0, 0, 0);
    }

    // ---- staging: plane zrp (rows yy = y0-1 .. y0+4) -> LDS buffer ----
#define STAGE(zrp, bufbase)                                                          \
    {   const int zz_ = z - 1 + (zrp);                                               \
        _Pragma("unroll") for (int c_ = 0; c_ < 6; ++c_) {                           \
            const int chunk_ = c_ * 4 + w;                                           \
            const int row_ = chunk_ >> 2, kc_ = chunk_ & 3;                          \
            const int yy_ = y0 - 1 + row_;                                           \
            const uint16_t* src_ = (zz_ >= 0 && zz_ < DD && yy_ >= 0 && yy_ < DD)    \
                ? xt + (((size_t)b * DD + zz_) * DD + yy_) * 2048 + kc_ * 512 + lane * 8 \
                : zp + lane * 8;                                                     \
            gll16(src_, &lds[(bufbase) + row_ * 4224u + 64u + kc_ * 1024u]);         \
        }                                                                            \
    }

    f32x16 acc[4];
#pragma unroll
    for (int ly = 0; ly < 4; ++ly)
#pragma unroll
        for (int i = 0; i < 16; ++i) acc[ly][i] = 0.f;

    // ---- compute phase for one z-plane (both ci-halves) ----
#define PHASE(zr, bufbase)                                                           \
    _Pragma("unroll") for (int cb_ = 0; cb_ < 2; ++cb_) {                            \
        bf16x8 wf[9];                                                                \
        _Pragma("unroll") for (int q_ = 0; q_ < 9; ++q_)                             \
            wf[q_] = *(const bf16x8*)(wpk + (size_t)((((zr) * 9 + q_) * 2 + cb_) * 2 + ct) * 512 + lane * 8); \
        const unsigned cc_ = (unsigned)(cb_ * 2 + h);                                \
        _Pragma("unroll") for (int t_ = 0; t_ < 6; ++t_) {                           \
            const unsigned rb_ = (unsigned)((bufbase) + t_ * 4224u);                 \
            bf16x8 bf[3];                                                            \
            _Pragma("unroll") for (int kx_ = 0; kx_ < 3; ++kx_) {                    \
                const unsigned sl_ = (unsigned)(xoff + u + kx_);                     \
                const unsigned s_ = ((sl_ - 1u) >> 1) & 3u;                          \
                bf[kx_] = *(const bf16x8*)&lds[rb_ + sl_ * 64u + ((cc_ ^ s_) << 4)]; \
            }                                                                        \
            _Pragma("unroll") for (int ly_ = 0; ly_ < 4; ++ly_) {                    \
                const int ky_ = t_ - ly_;                                            \
                if (ky_ >= 0 && ky_ <= 2) {                                          \
                    _Pragma("unroll") for (int kx_ = 0; kx_ < 3; ++kx_)              \
                        acc[ly_] = __builtin_amdgcn_mfma_f32_32x32x16_bf16(          \
                            wf[ky_ * 3 + kx_], bf[kx_], acc[ly_], 0, 0, 0);          \
                }                                                                    \
            }                                                                        \
        }                                                                            \
    }

    // ---- pipeline: p0->A, p1->B | zr0(A) | p2->A, zr1(B) | zr2(A) ----
    STAGE(0, 0u)
    STAGE(1, BUF_STRIDE)
    __syncthreads();                 // drains vmcnt: planes 0,1 resident
    PHASE(0, 0u)
    __syncthreads();                 // all waves done reading buf A
    STAGE(2, 0u)                     // issue plane 2 -> A (in flight during zr1)
    PHASE(1, BUF_STRIDE)
    __syncthreads();                 // drains vmcnt: plane 2 resident
    PHASE(2, 0u)

#undef STAGE
#undef PHASE

    // ---- epilogue: +bias, x mask, store. C: col=u (x), row=(r&3)+8*(r>>2)+4*h (co) ----
    const size_t mb0 = (((size_t)b * DD + z) * DD + y0) * DD + xoff + u;
    float m[4];
#pragma unroll
    for (int ly = 0; ly < 4; ++ly) m[ly] = mask[mb0 + ly * DD] ? 1.0f : 0.0f;
#pragma unroll
    for (int r = 0; r < 16; ++r) {
        const int co = ct * 32 + (r & 3) + 8 * (r >> 2) + 4 * h;
        const float bs = bias[co];
        const size_t o = ((size_t)b * COUT + co) * (DD * DD * DD)
                       + (size_t)z * (DD * DD) + (size_t)y0 * DD + xoff + u;
#pragma unroll
        for (int ly = 0; ly < 4; ++ly)
            out[o + ly * DD] = (acc[ly][r] + bs) * m[ly];
    }
}

// ---------------- fp32 fallback (ws too small) ----------------
#define CI_BLK 16
__global__ __launch_bounds__(256, 2)
void sparse_conv3d_f32(const float* __restrict__ x,
                       const int* __restrict__ mask,
                       const float* __restrict__ weight,
                       const float* __restrict__ bias,
                       float* __restrict__ out) {
    __shared__ float lds[9 * CI_BLK * 66];
    const int y = blockIdx.x, z = blockIdx.y, b = blockIdx.z;
    const int lane = threadIdx.x & 63;
    const int wave = __builtin_amdgcn_readfirstlane(threadIdx.x >> 6);
    float acc[16];
#pragma unroll
    for (int j = 0; j < 16; ++j) acc[j] = 0.0f;
    const int co0 = wave * 16;
    const float* wbase = weight + (size_t)co0 * (CIN * 27);
    for (int cbl = 0; cbl < 2; ++cbl) {
        if (cbl) __syncthreads();
        for (int i = wave; i < 9 * CI_BLK; i += 4) {
            const int r = i >> 4, ci_l = i & 15;
            const int zz = z + (r / 3) - 1, yy = y + (r % 3) - 1;
            const int ci = cbl * CI_BLK + ci_l;
            float v = 0.0f;
            if (zz >= 0 && zz < DD && yy >= 0 && yy < DD)
                v = x[((((size_t)b * CIN + ci) * DD + zz) * DD + yy) * DD + lane];
            float* row = &lds[(size_t)i * 66];
            row[1 + lane] = v;
            if (lane == 0) { row[0] = 0.0f; row[65] = 0.0f; }
        }
        __syncthreads();
        for (int ci_l = 0; ci_l < CI_BLK; ++ci_l) {
            const int ci = cbl * CI_BLK + ci_l;
#pragma unroll
            for (int kz = 0; kz < 3; ++kz) {
#pragma unroll
                for (int ky = 0; ky < 3; ++ky) {
                    const int r = kz * 3 + ky;
                    const float* xrow = &lds[(size_t)(r * CI_BLK + ci_l) * 66 + lane];
                    const float xv0 = xrow[0], xv1 = xrow[1], xv2 = xrow[2];
                    const float* wp = wbase + ci * 27 + kz * 9 + ky * 3;
#pragma unroll
                    for (int j = 0; j < 16; ++j) {
                        acc[j] += wp[(size_t)j * (CIN * 27) + 0] * xv0
                                + wp[(size_t)j * (CIN * 27) + 1] * xv1
                                + wp[(size_t)j * (CIN * 27) + 2] * xv2;
                    }
                }
            }
        }
    }
    const float m = mask[(((size_t)b * DD + z) * DD + y) * DD + lane] ? 1.0f : 0.0f;
#pragma unroll
    for (int j = 0; j < 16; ++j) {
        const int co = co0 + j;
        out[((((size_t)b * COUT + co) * DD + z) * DD + y) * DD + lane] = (acc[j] + bias[co]) * m;
    }
}

extern "C" void kernel_launch(void* const* d_in, const int* in_sizes, int n_in,
                              void* d_out, int out_size, void* d_ws, size_t ws_size,
                              hipStream_t stream) {
    const float* x    = (const float*)d_in[0];
    const int*   mask = (const int*)d_in[1];
    const float* w    = (const float*)d_in[2];
    const float* bias = (const float*)d_in[3];
    float*       out  = (float*)d_out;

    if (ws_size < WS_NEEDED) {
        sparse_conv3d_f32<<<dim3(DD, DD, 2), 256, 0, stream>>>(x, mask, w, bias, out);
        return;
    }

    uint16_t* xt  = (uint16_t*)d_ws;
    uint16_t* wpk = (uint16_t*)((char*)d_ws + XT_BYTES);
    uint16_t* zp  = (uint16_t*)((char*)d_ws + XT_BYTES + WPK_BYTES);

    pack_weights<<<(WPK_U16 + ZP_BYTES / 16 + 255) / 256, 256, 0, stream>>>(w, wpk, (uint4*)zp);
    transpose_x<<<dim3(DD, DD, 2), 256, 0, stream>>>(x, xt);
    conv_mfma<<<dim3(DD / 4, DD, 2), 256, CONV_LDS, stream>>>(xt, wpk, zp, mask, bias, out);
}